// Round 18
// baseline (216.002 us; speedup 1.0000x reference)
//
#include <hip/hip_runtime.h>
#include <hip/hip_bf16.h>

typedef __attribute__((ext_vector_type(8))) short bf16x8;
typedef __attribute__((ext_vector_type(4))) short short4v;
typedef __attribute__((ext_vector_type(4))) float f32x4;
typedef __attribute__((ext_vector_type(16))) float f32x16;
typedef __attribute__((ext_vector_type(4))) unsigned int uint4v;

// ---- bf16 bit helpers (RNE, finite inputs) ----
__device__ inline unsigned short f2b(float f){
  unsigned int u = __float_as_uint(f);
  unsigned int r = (u + 0x7fffu + ((u >> 16) & 1u)) >> 16;
  return (unsigned short)r;
}
__device__ inline float b2f(unsigned short u){
  return __uint_as_float(((unsigned int)u) << 16);
}
// truncation pack for P>0 (3 ops). HW v_cvt_pk_bf16_f32 banned (R3/R12).
__device__ inline unsigned int pk_tr(float lo, float hi){
  return (__float_as_uint(hi) & 0xffff0000u) | (__float_as_uint(lo) >> 16);
}
// branch-free tanh-GELU (max dev from exact erf-GELU ~3e-4)
__device__ inline float gelu_tanh(float x){
  float x3 = x*x*x;
  float y = 0.79788456080286536f*x + 0.035677408136300125f*x3;
  float a = fminf(y * 2.8853900817779268f, 80.f);
  float t = __builtin_amdgcn_exp2f(a);
  return x * t * __builtin_amdgcn_rcpf(t + 1.f);
}

// ---- fused prep: 4 weight transposes (fp32->bf16^T) + x convert ----
__global__ __launch_bounds__(256) void prep_kernel(
    const float* __restrict__ Wqkv, short* __restrict__ WqkvT,
    const float* __restrict__ Wo,   short* __restrict__ WoT,
    const float* __restrict__ W1,   short* __restrict__ W1T,
    const float* __restrict__ W2,   short* __restrict__ W2T,
    const float* __restrict__ x,    short* __restrict__ xb){
  __shared__ float tile[32][33];
  const int b = blockIdx.x;
  const float* A; short* AT; int R, C, bx, by;
  if (b < 1728){ A=Wqkv; AT=WqkvT; R=768;  C=2304; bx=b%72;        by=b/72; }
  else if (b < 2304){ int c=b-1728; A=Wo; AT=WoT; R=768;  C=768;  bx=c%24; by=c/24; }
  else if (b < 4608){ int c=b-2304; A=W1; AT=W1T; R=768;  C=3072; bx=c%96; by=c/96; }
  else if (b < 6912){ int c=b-4608; A=W2; AT=W2T; R=3072; C=768;  bx=c%24; by=c/24; }
  else {
    int i = (b - 6912)*256 + threadIdx.x;
    float4 v = reinterpret_cast<const float4*>(x)[i];
    short4v o;
    o[0] = (short)f2b(v.x); o[1] = (short)f2b(v.y);
    o[2] = (short)f2b(v.z); o[3] = (short)f2b(v.w);
    reinterpret_cast<short4v*>(xb)[i] = o;
    return;
  }
  const int tx = threadIdx.x & 31, ty = threadIdx.x >> 5;
  const int c0 = bx*32, r0 = by*32;
  #pragma unroll
  for (int i = 0; i < 4; i++)
    tile[ty + i*8][tx] = A[(size_t)(r0 + ty + i*8)*C + c0 + tx];
  __syncthreads();
  #pragma unroll
  for (int i = 0; i < 4; i++){
    int c = c0 + ty + i*8, r = r0 + tx;
    AT[(size_t)c*R + r] = (short)f2b(tile[tx][ty + i*8]);
  }
}

// ---- GEMM: C[M,N] = A[M,K(slice)] @ BT^T + epilogue ----
// Depth-2 counted-vmcnt pipeline, XOR-swizzled LDS, 2D XCD chunking,
// K-rotation convoy-breaker, optional split-K (OUTMODE 3: raw fp32 partial).
// OUTMODE: 1 = bf16 out (+GELU), 2 = qkv fragment-packed split, 3 = partial.
template<int OUTMODE, int GELU>
__global__ __launch_bounds__(256) void gemm_kernel(
    const short* __restrict__ A, const short* __restrict__ BT,
    const float* __restrict__ bias,
    float* __restrict__ outF, float* __restrict__ outF2,
    short* __restrict__ outB, short* __restrict__ outB2, short* __restrict__ outB3,
    int M, int N, int K, int ksplit, int nper, int G, int cpr, int byc)
{
  __shared__ short As[3][128*32];
  __shared__ short Bs[3][128*32];
  const int sb = blockIdx.x / nper;      // split index
  const int b2 = blockIdx.x % nper;
  const int kbase = sb * ksplit;
  const int xcd = b2 & 7, r = b2 >> 3;
  const int bx = (xcd % cpr)*G + (r % G);
  const int by = (xcd / cpr)*byc + (r / G);
  const int m0 = by * 128, n0 = bx * 128;

  const int lane = threadIdx.x & 63, wid = threadIdx.x >> 6;
  const int l15 = lane & 15, l4 = lane >> 4;
  const int wr = wid >> 1, wc = wid & 1;

  f32x4 acc[4][4];
  #pragma unroll
  for (int i = 0; i < 4; i++)
    #pragma unroll
    for (int j = 0; j < 4; j++) acc[i][j] = (f32x4){0.f,0.f,0.f,0.f};

  const int arow = wid*16 + (lane >> 2);
  const int sswz = (((lane & 3) ^ ((lane >> 3) & 3))) * 8;
  const short* Ag = A  + (size_t)(m0 + arow)*K + sswz;
  const short* Bg = BT + (size_t)(n0 + arow)*K + sswz;

  const int NT = ksplit >> 5;
  const int rot = b2 % NT;               // convoy-breaking K rotation
  auto kof = [&](int i){ int tt = i + rot; if (tt >= NT) tt -= NT; return kbase + (tt << 5); };

  auto STAGE = [&](int buf, int k0){
    #pragma unroll
    for (int p = 0; p < 2; p++){
      __builtin_amdgcn_global_load_lds(
          (const __attribute__((address_space(1))) void*)(Ag + (size_t)p*64*K + k0),
          (__attribute__((address_space(3))) void*)(&As[buf][(p*64 + wid*16)*32]), 16, 0, 0);
      __builtin_amdgcn_global_load_lds(
          (const __attribute__((address_space(1))) void*)(Bg + (size_t)p*64*K + k0),
          (__attribute__((address_space(3))) void*)(&Bs[buf][(p*64 + wid*16)*32]), 16, 0, 0);
    }
  };

  STAGE(0, kof(0));
  STAGE(1, kof(1));

  const int rchunk = (l15 >> 1) & 3;
  int cur = 0;
  for (int t = 0; t < NT; t++){
    if (t + 1 < NT) asm volatile("s_waitcnt vmcnt(4)" ::: "memory");
    else            asm volatile("s_waitcnt vmcnt(0)" ::: "memory");
    __builtin_amdgcn_s_barrier();
    __builtin_amdgcn_sched_barrier(0);
    const short* as = &As[cur][0];
    const short* bs = &Bs[cur][0];
    bf16x8 av[4], bv[4];
    #pragma unroll
    for (int i = 0; i < 4; i++)
      av[i] = *(const bf16x8*)(as + (wr*64 + i*16 + l15)*32 + ((l4 ^ rchunk) * 8));
    #pragma unroll
    for (int i = 0; i < 4; i++)
      bv[i] = *(const bf16x8*)(bs + (wc*64 + i*16 + l15)*32 + ((l4 ^ rchunk) * 8));
    #pragma unroll
    for (int i = 0; i < 4; i++)
      #pragma unroll
      for (int j = 0; j < 4; j++)
        acc[i][j] = __builtin_amdgcn_mfma_f32_16x16x32_bf16(av[i], bv[j], acc[i][j], 0, 0, 0);
    if (t + 2 < NT){
      int s2 = cur + 2; if (s2 >= 3) s2 -= 3;
      STAGE(s2, kof(t + 2));
    }
    cur = (cur == 2) ? 0 : cur + 1;
  }

  if constexpr (OUTMODE == 2){
    const float SCQ = 0.125f * 1.44269504088896341f;
    #pragma unroll
    for (int i = 0; i < 4; i++){
      const int row0 = m0 + wr*64 + i*16 + l4*4;
      const size_t rQK = (size_t)(row0>>5)*2048 + (size_t)(row0&31)*8;
      // permuted V slot: ks=(row>>4)&1, hi'=(row>>2)&1, i0=4*((row>>3)&1)
      const size_t rV  = (size_t)(row0>>5)*2048 + (size_t)((row0>>4)&1)*1024
                       + (size_t)((row0>>2)&1)*256 + (size_t)((row0>>3)&1)*4;
      #pragma unroll
      for (int j = 0; j < 4; j++){
        const int col = n0 + wc*64 + j*16 + l15;
        const float bval = bias[col];
        if (col < 1536){
          const int isQ = (col < 768);
          const float qs = isQ ? SCQ : 1.f;
          const int c2 = isQ ? col : (col - 768);
          short* dst = isQ ? outB : outB2;
          const int head = c2 >> 6, dh = c2 & 63;
          const size_t base = (size_t)head*262144 + (size_t)(dh>>4)*512
                            + (size_t)((dh>>3)&1)*256 + (size_t)(dh&7) + rQK;
          dst[base]      = (short)f2b((acc[i][j][0] + bval) * qs);
          dst[base + 8]  = (short)f2b((acc[i][j][1] + bval) * qs);
          dst[base + 16] = (short)f2b((acc[i][j][2] + bval) * qs);
          dst[base + 24] = (short)f2b((acc[i][j][3] + bval) * qs);
        } else {
          const int c2 = col - 1536;
          const int head = c2 >> 6, dh = c2 & 63;
          const size_t base = (size_t)head*262144 + (size_t)(dh>>5)*512
                            + (size_t)(dh&31)*8 + rV;
          short4v sv;
          sv[0] = (short)f2b(acc[i][j][0] + bval);
          sv[1] = (short)f2b(acc[i][j][1] + bval);
          sv[2] = (short)f2b(acc[i][j][2] + bval);
          sv[3] = (short)f2b(acc[i][j][3] + bval);
          *(short4v*)(outB3 + base) = sv;
        }
      }
    }
  } else if constexpr (OUTMODE == 3){
    float* dst = sb ? outF2 : outF;
    #pragma unroll
    for (int i = 0; i < 4; i++){
      const int row0 = m0 + wr*64 + i*16 + l4*4;
      #pragma unroll
      for (int j = 0; j < 4; j++){
        const int col = n0 + wc*64 + j*16 + l15;
        #pragma unroll
        for (int jj = 0; jj < 4; jj++)
          dst[(size_t)(row0 + jj)*N + col] = acc[i][j][jj];
      }
    }
  } else {
    #pragma unroll
    for (int i = 0; i < 4; i++){
      const int row0 = m0 + wr*64 + i*16 + l4*4;
      #pragma unroll
      for (int j = 0; j < 4; j++){
        const int col = n0 + wc*64 + j*16 + l15;
        const float bval = bias[col];
        #pragma unroll
        for (int jj = 0; jj < 4; jj++){
          float v = acc[i][j][jj] + bval;
          if constexpr (GELU) v = gelu_tanh(v);
          outB[(size_t)(row0 + jj)*N + col] = (short)f2b(v);
        }
      }
    }
  }
}

// ---- flash attention v11: split S-chain (2 independent 2-MFMA chains),
// zero-routing PV, l-sum via ones-MFMA, zero-C trick. Zero-LDS main loop.
__global__ __launch_bounds__(256) void attn11_kernel(
    const short* __restrict__ Qf, const short* __restrict__ Kf,
    const short* __restrict__ Vf, short* __restrict__ hout){
  __shared__ float Ols[4][32][33];
  __shared__ float Lls[4][32];
  const int g = (blockIdx.x & 7) * 192 + (blockIdx.x >> 3);
  const int head = g >> 7;
  const int qt = g & 127;
  const int lane = threadIdx.x & 63, w = threadIdx.x >> 6;
  const int l31 = lane & 31, hi = lane >> 5;

  bf16x8 qf0, qf1, qf2, qf3;
  {
    const short* qp = Qf + (size_t)(head*128 + qt)*2048 + lane*8;
    qf0 = *(const bf16x8*)(qp);
    qf1 = *(const bf16x8*)(qp + 512);
    qf2 = *(const bf16x8*)(qp + 1024);
    qf3 = *(const bf16x8*)(qp + 1536);
  }

  // constants: ones A-fragment (bf16 1.0) and zero C bank
  bf16x8 ones;
  #pragma unroll
  for (int i = 0; i < 8; i++) ones[i] = (short)0x3F80;
  f32x16 zro;
  #pragma unroll
  for (int r = 0; r < 16; r++) zro[r] = 0.f;

  f32x16 o0, o1, ol;
  #pragma unroll
  for (int r = 0; r < 16; r++){ o0[r] = 0.f; o1[r] = 0.f; ol[r] = 0.f; }

  const short* kp0 = Kf + (size_t)(head*128 + w*32)*2048 + lane*8;
  const short* vp0 = Vf + (size_t)(head*128 + w*32)*2048 + lane*8;

  auto PROC = [&](bf16x8 k0, bf16x8 k1, bf16x8 k2, bf16x8 k3, int t){
    const short* vp = vp0 + t*2048;
    bf16x8 v00 = *(const bf16x8*)(vp);            // ks=0, db=0 (permuted slots)
    bf16x8 v01 = *(const bf16x8*)(vp + 512);      // ks=0, db=1
    bf16x8 v10 = *(const bf16x8*)(vp + 1024);     // ks=1, db=0
    bf16x8 v11 = *(const bf16x8*)(vp + 1536);     // ks=1, db=1

    // S^T over d=64: two INDEPENDENT 2-MFMA chains (halved serial latency)
    f32x16 sa, sb;
    sa = __builtin_amdgcn_mfma_f32_32x32x16_bf16(k0, qf0, zro, 0, 0, 0);
    sb = __builtin_amdgcn_mfma_f32_32x32x16_bf16(k2, qf2, zro, 0, 0, 0);
    sa = __builtin_amdgcn_mfma_f32_32x32x16_bf16(k1, qf1, sa, 0, 0, 0);
    sb = __builtin_amdgcn_mfma_f32_32x32x16_bf16(k3, qf3, sb, 0, 0, 0);

    float s[16];
    #pragma unroll
    for (int r = 0; r < 16; r++)
      s[r] = __builtin_amdgcn_exp2f(sa[r] + sb[r]);

    // P^T B-fragments: lane-local pack only (V slot permutation absorbs routing)
    uint4v u0 = { pk_tr(s[0], s[1]),  pk_tr(s[2], s[3]),
                  pk_tr(s[4], s[5]),  pk_tr(s[6], s[7]) };
    uint4v u1 = { pk_tr(s[8], s[9]),  pk_tr(s[10], s[11]),
                  pk_tr(s[12], s[13]), pk_tr(s[14], s[15]) };
    bf16x8 pb0 = __builtin_bit_cast(bf16x8, u0);
    bf16x8 pb1 = __builtin_bit_cast(bf16x8, u1);

    // l-sum via ones-MFMA (contracts across both lane halves' slots)
    ol = __builtin_amdgcn_mfma_f32_32x32x16_bf16(ones, pb0, ol, 0, 0, 0);
    ol = __builtin_amdgcn_mfma_f32_32x32x16_bf16(ones, pb1, ol, 0, 0, 0);

    o0 = __builtin_amdgcn_mfma_f32_32x32x16_bf16(v00, pb0, o0, 0, 0, 0);
    o0 = __builtin_amdgcn_mfma_f32_32x32x16_bf16(v10, pb1, o0, 0, 0, 0);
    o1 = __builtin_amdgcn_mfma_f32_32x32x16_bf16(v01, pb0, o1, 0, 0, 0);
    o1 = __builtin_amdgcn_mfma_f32_32x32x16_bf16(v11, pb1, o1, 0, 0, 0);
  };

  bf16x8 kA0 = *(const bf16x8*)(kp0);
  bf16x8 kA1 = *(const bf16x8*)(kp0 + 512);
  bf16x8 kA2 = *(const bf16x8*)(kp0 + 1024);
  bf16x8 kA3 = *(const bf16x8*)(kp0 + 1536);
  for (int t = 0; t < 32; t += 2){
    const short* kpB = kp0 + (t+1)*2048;
    bf16x8 kB0 = *(const bf16x8*)(kpB);
    bf16x8 kB1 = *(const bf16x8*)(kpB + 512);
    bf16x8 kB2 = *(const bf16x8*)(kpB + 1024);
    bf16x8 kB3 = *(const bf16x8*)(kpB + 1536);
    PROC(kA0, kA1, kA2, kA3, t);
    const short* kpA = kp0 + ((t+2 < 32) ? (t+2) : 31)*2048;
    kA0 = *(const bf16x8*)(kpA);
    kA1 = *(const bf16x8*)(kpA + 512);
    kA2 = *(const bf16x8*)(kpA + 1024);
    kA3 = *(const bf16x8*)(kpA + 1536);
    PROC(kB0, kB1, kB2, kB3, t+1);
  }

  if (hi == 0) Lls[w][l31] = ol[0];
  #pragma unroll
  for (int r = 0; r < 16; r++){
    int d = (r & 3) + 8*(r >> 2) + 4*hi;
    Ols[w][l31][d] = o0[r];
  }
  __syncthreads();
  const int t = threadIdx.x;
  const int q = t >> 2, dc = (t & 3) * 8;
  float inv;
  if (t < 128){
    float l = Lls[0][q] + Lls[1][q] + Lls[2][q] + Lls[3][q];
    inv = 1.f / l;
    bf16x8 res;
    #pragma unroll
    for (int j = 0; j < 8; j++){
      float o = Ols[0][q][dc+j] + Ols[1][q][dc+j]
              + Ols[2][q][dc+j] + Ols[3][q][dc+j];
      res[j] = (short)f2b(o * inv);
    }
    *(bf16x8*)(hout + (size_t)(qt*32 + q)*768 + head*64 + dc) = res;
  }
  __syncthreads();
  #pragma unroll
  for (int r = 0; r < 16; r++){
    int d = (r & 3) + 8*(r >> 2) + 4*hi;
    Ols[w][l31][d] = o1[r];
  }
  __syncthreads();
  if (t < 128){
    bf16x8 res;
    #pragma unroll
    for (int j = 0; j < 8; j++){
      float o = Ols[0][q][dc+j] + Ols[1][q][dc+j]
              + Ols[2][q][dc+j] + Ols[3][q][dc+j];
      res[j] = (short)f2b(o * inv);
    }
    *(bf16x8*)(hout + (size_t)(qt*32 + q)*768 + head*64 + 32 + dc) = res;
  }
}

// ---- LayerNorm with split-K merge: v = p0 + p1 + resid + cbias ----
template<int WRITE_BF16>
__global__ __launch_bounds__(256) void ln_merge_kernel(
    const float* __restrict__ p0, const float* __restrict__ p1,
    const float* __restrict__ resid, const float* __restrict__ cbias,
    const float* __restrict__ g, const float* __restrict__ b,
    float* __restrict__ outF, short* __restrict__ outB){
  const int row = blockIdx.x;
  const size_t base = (size_t)row * 768;
  const int t = threadIdx.x;
  float v[3];
  #pragma unroll
  for (int i = 0; i < 3; i++){
    int c = t + i*256;
    v[i] = p0[base + c] + p1[base + c] + resid[base + c] + cbias[c];
  }
  float s  = v[0] + v[1] + v[2];
  float s2 = v[0]*v[0] + v[1]*v[1] + v[2]*v[2];
  #pragma unroll
  for (int off = 1; off < 64; off <<= 1){
    s  += __shfl_xor(s,  off);
    s2 += __shfl_xor(s2, off);
  }
  __shared__ float red[8];
  if ((t & 63) == 0){ red[t >> 6] = s; red[4 + (t >> 6)] = s2; }
  __syncthreads();
  s  = red[0] + red[1] + red[2] + red[3];
  s2 = red[4] + red[5] + red[6] + red[7];
  const float mean = s * (1.f/768.f);
  const float rstd = rsqrtf(s2*(1.f/768.f) - mean*mean + 1e-5f);
  #pragma unroll
  for (int i = 0; i < 3; i++){
    int c = t + i*256;
    float y = g[c] * ((v[i] - mean) * rstd) + b[c];
    outF[base + c] = y;
    if constexpr (WRITE_BF16) outB[base + c] = (short)f2b(y);
  }
}

extern "C" void kernel_launch(void* const* d_in, const int* in_sizes, int n_in,
                              void* d_out, int out_size, void* d_ws, size_t ws_size,
                              hipStream_t stream){
  const float* x    = (const float*)d_in[0];
  const float* Wqkv = (const float*)d_in[1];
  const float* bqkv = (const float*)d_in[2];
  const float* Wo   = (const float*)d_in[3];
  const float* bo   = (const float*)d_in[4];
  const float* ln1w = (const float*)d_in[5];
  const float* ln1b = (const float*)d_in[6];
  const float* W1   = (const float*)d_in[7];
  const float* b1   = (const float*)d_in[8];
  const float* W2   = (const float*)d_in[9];
  const float* b2   = (const float*)d_in[10];
  const float* ln2w = (const float*)d_in[11];
  const float* ln2b = (const float*)d_in[12];
  float* out = (float*)d_out;

  char* ws = (char*)d_ws;
  short* WqkvT = (short*)(ws + 0);          //  2304x768 bf16
  short* WoT   = (short*)(ws + 3538944);    //   768x768
  short* W1T   = (short*)(ws + 4718592);    //  3072x768
  short* W2T   = (short*)(ws + 9437184);    //   768x3072
  short* xb    = (short*)(ws + 14155776);   //  4096x768
  short* Qfb   = (short*)(ws + 20447232);   //  12x128x2048 packed Q fragments
  short* Kfb   = (short*)(ws + 26738688);   //  12x128x2048 packed K fragments
  short* Vfb   = (short*)(ws + 33030144);   //  12x128x2048 packed V fragments
  short* hb    = (short*)(ws + 39321600);   //  4096x768
  float* res1  = (float*)(ws + 45613056);   //  fp32 plane (FFN2 partial 0)
  float* x1f   = (float*)(ws + 58195968);   //  4096x768 fp32
  short* x1b   = (short*)(ws + 70778880);   //  4096x768
  short* h1b   = (short*)(ws + 77070336);   //  4096x3072 (also Wo partials 0/1)
  float* woP   = (float*)(ws + 77070336);   //  2 fp32 planes (pre-FFN1)
  float* f2P1  = (float*)(ws + 20447232);   //  fp32 plane (Qf/Kf region, post-attn)
  const int PLANE = 4096*768;

  dim3 blk(256);
  // fused transposes + x convert (9984 blocks)
  prep_kernel<<<dim3(9984), blk, 0, stream>>>(
      Wqkv, WqkvT, Wo, WoT, W1, W1T, W2, W2T, x, xb);

  // qkv = x @ Wqkv + bqkv -> fragment-packed Q/K/V (Q pre-scaled); 576 blocks, chunk 9x8
  gemm_kernel<2,0><<<dim3(576), blk, 0, stream>>>(
      xb, WqkvT, bqkv, nullptr, nullptr, Qfb, Kfb, Vfb,
      4096, 2304, 768, 768, 576, 9, 2, 8);
  // flash attention -> h bf16 (1536 blocks, XCD-chunked)
  attn11_kernel<<<dim3(1536), blk, 0, stream>>>(Qfb, Kfb, Vfb, hb);
  // h @ Wo split-K=2 -> fp32 partials in h1b region (384 blocks, chunk 6x4)
  gemm_kernel<3,0><<<dim3(384), blk, 0, stream>>>(
      hb, WoT, nullptr, woP, woP + PLANE, nullptr, nullptr, nullptr,
      4096, 768, 768, 384, 192, 6, 1, 4);
  // x1 = LN1(p0 + p1 + x + bo)
  ln_merge_kernel<1><<<dim3(4096), blk, 0, stream>>>(
      woP, woP + PLANE, x, bo, ln1w, ln1b, x1f, x1b);
  // h1 = gelu(x1 @ W1 + b1) bf16; 768 blocks, chunk 12x8
  gemm_kernel<1,1><<<dim3(768), blk, 0, stream>>>(
      x1b, W1T, b1, nullptr, nullptr, h1b, nullptr, nullptr,
      4096, 3072, 768, 768, 768, 12, 2, 8);
  // h1 @ W2 split-K=2 -> fp32 partials res1 / f2P1 (384 blocks, chunk 6x4)
  gemm_kernel<3,0><<<dim3(384), blk, 0, stream>>>(
      h1b, W2T, nullptr, res1, f2P1, nullptr, nullptr, nullptr,
      4096, 768, 3072, 1536, 192, 6, 1, 4);
  // out = LN2(q0 + q1 + x1 + b2)
  ln_merge_kernel<0><<<dim3(4096), blk, 0, stream>>>(
      res1, f2P1, x1f, b2, ln2w, ln2b, out, nullptr);
}

// Round 19
// 208.670 us; speedup vs baseline: 1.0351x; 1.0351x over previous
//
#include <hip/hip_runtime.h>
#include <hip/hip_bf16.h>

typedef __attribute__((ext_vector_type(8))) short bf16x8;
typedef __attribute__((ext_vector_type(4))) short short4v;
typedef __attribute__((ext_vector_type(4))) float f32x4;
typedef __attribute__((ext_vector_type(16))) float f32x16;
typedef __attribute__((ext_vector_type(4))) unsigned int uint4v;

// ---- bf16 bit helpers (RNE, finite inputs) ----
__device__ inline unsigned short f2b(float f){
  unsigned int u = __float_as_uint(f);
  unsigned int r = (u + 0x7fffu + ((u >> 16) & 1u)) >> 16;
  return (unsigned short)r;
}
__device__ inline float b2f(unsigned short u){
  return __uint_as_float(((unsigned int)u) << 16);
}
// truncation pack for P>0 (3 ops). HW v_cvt_pk_bf16_f32 banned (R3/R12).
__device__ inline unsigned int pk_tr(float lo, float hi){
  return (__float_as_uint(hi) & 0xffff0000u) | (__float_as_uint(lo) >> 16);
}
__device__ inline float pair_sum(float x){
  return x + __shfl_xor(x, 32);
}
// branch-free tanh-GELU (max dev from exact erf-GELU ~3e-4)
__device__ inline float gelu_tanh(float x){
  float x3 = x*x*x;
  float y = 0.79788456080286536f*x + 0.035677408136300125f*x3;
  float a = fminf(y * 2.8853900817779268f, 80.f);
  float t = __builtin_amdgcn_exp2f(a);
  return x * t * __builtin_amdgcn_rcpf(t + 1.f);
}

// ---- fused prep: 4 weight transposes (fp32->bf16^T) + x convert ----
__global__ __launch_bounds__(256) void prep_kernel(
    const float* __restrict__ Wqkv, short* __restrict__ WqkvT,
    const float* __restrict__ Wo,   short* __restrict__ WoT,
    const float* __restrict__ W1,   short* __restrict__ W1T,
    const float* __restrict__ W2,   short* __restrict__ W2T,
    const float* __restrict__ x,    short* __restrict__ xb){
  __shared__ float tile[32][33];
  const int b = blockIdx.x;
  const float* A; short* AT; int R, C, bx, by;
  if (b < 1728){ A=Wqkv; AT=WqkvT; R=768;  C=2304; bx=b%72;        by=b/72; }
  else if (b < 2304){ int c=b-1728; A=Wo; AT=WoT; R=768;  C=768;  bx=c%24; by=c/24; }
  else if (b < 4608){ int c=b-2304; A=W1; AT=W1T; R=768;  C=3072; bx=c%96; by=c/96; }
  else if (b < 6912){ int c=b-4608; A=W2; AT=W2T; R=3072; C=768;  bx=c%24; by=c/24; }
  else {
    int i = (b - 6912)*256 + threadIdx.x;
    float4 v = reinterpret_cast<const float4*>(x)[i];
    short4v o;
    o[0] = (short)f2b(v.x); o[1] = (short)f2b(v.y);
    o[2] = (short)f2b(v.z); o[3] = (short)f2b(v.w);
    reinterpret_cast<short4v*>(xb)[i] = o;
    return;
  }
  const int tx = threadIdx.x & 31, ty = threadIdx.x >> 5;
  const int c0 = bx*32, r0 = by*32;
  #pragma unroll
  for (int i = 0; i < 4; i++)
    tile[ty + i*8][tx] = A[(size_t)(r0 + ty + i*8)*C + c0 + tx];
  __syncthreads();
  #pragma unroll
  for (int i = 0; i < 4; i++){
    int c = c0 + ty + i*8, r = r0 + tx;
    AT[(size_t)c*R + r] = (short)f2b(tile[tx][ty + i*8]);
  }
}

// ---- GEMM: C[M,N] = A[M,K(slice)] @ BT^T + epilogue ----
// Depth-2 counted-vmcnt pipeline, XOR-swizzled LDS, 2D XCD chunking,
// K-rotation convoy-breaker, optional split-K (OUTMODE 3: raw fp32 partial).
// OUTMODE: 1 = bf16 out (+GELU), 2 = qkv fragment-packed split, 3 = partial.
template<int OUTMODE, int GELU>
__global__ __launch_bounds__(256) void gemm_kernel(
    const short* __restrict__ A, const short* __restrict__ BT,
    const float* __restrict__ bias,
    float* __restrict__ outF, float* __restrict__ outF2,
    short* __restrict__ outB, short* __restrict__ outB2, short* __restrict__ outB3,
    int M, int N, int K, int ksplit, int nper, int G, int cpr, int byc)
{
  __shared__ short As[3][128*32];
  __shared__ short Bs[3][128*32];
  const int sb = blockIdx.x / nper;      // split index
  const int b2 = blockIdx.x % nper;
  const int kbase = sb * ksplit;
  const int xcd = b2 & 7, r = b2 >> 3;
  const int bx = (xcd % cpr)*G + (r % G);
  const int by = (xcd / cpr)*byc + (r / G);
  const int m0 = by * 128, n0 = bx * 128;

  const int lane = threadIdx.x & 63, wid = threadIdx.x >> 6;
  const int l15 = lane & 15, l4 = lane >> 4;
  const int wr = wid >> 1, wc = wid & 1;

  f32x4 acc[4][4];
  #pragma unroll
  for (int i = 0; i < 4; i++)
    #pragma unroll
    for (int j = 0; j < 4; j++) acc[i][j] = (f32x4){0.f,0.f,0.f,0.f};

  const int arow = wid*16 + (lane >> 2);
  const int sswz = (((lane & 3) ^ ((lane >> 3) & 3))) * 8;
  const short* Ag = A  + (size_t)(m0 + arow)*K + sswz;
  const short* Bg = BT + (size_t)(n0 + arow)*K + sswz;

  const int NT = ksplit >> 5;
  const int rot = b2 % NT;               // convoy-breaking K rotation
  auto kof = [&](int i){ int tt = i + rot; if (tt >= NT) tt -= NT; return kbase + (tt << 5); };

  auto STAGE = [&](int buf, int k0){
    #pragma unroll
    for (int p = 0; p < 2; p++){
      __builtin_amdgcn_global_load_lds(
          (const __attribute__((address_space(1))) void*)(Ag + (size_t)p*64*K + k0),
          (__attribute__((address_space(3))) void*)(&As[buf][(p*64 + wid*16)*32]), 16, 0, 0);
      __builtin_amdgcn_global_load_lds(
          (const __attribute__((address_space(1))) void*)(Bg + (size_t)p*64*K + k0),
          (__attribute__((address_space(3))) void*)(&Bs[buf][(p*64 + wid*16)*32]), 16, 0, 0);
    }
  };

  STAGE(0, kof(0));
  STAGE(1, kof(1));

  const int rchunk = (l15 >> 1) & 3;
  int cur = 0;
  for (int t = 0; t < NT; t++){
    if (t + 1 < NT) asm volatile("s_waitcnt vmcnt(4)" ::: "memory");
    else            asm volatile("s_waitcnt vmcnt(0)" ::: "memory");
    __builtin_amdgcn_s_barrier();
    __builtin_amdgcn_sched_barrier(0);
    const short* as = &As[cur][0];
    const short* bs = &Bs[cur][0];
    bf16x8 av[4], bv[4];
    #pragma unroll
    for (int i = 0; i < 4; i++)
      av[i] = *(const bf16x8*)(as + (wr*64 + i*16 + l15)*32 + ((l4 ^ rchunk) * 8));
    #pragma unroll
    for (int i = 0; i < 4; i++)
      bv[i] = *(const bf16x8*)(bs + (wc*64 + i*16 + l15)*32 + ((l4 ^ rchunk) * 8));
    #pragma unroll
    for (int i = 0; i < 4; i++)
      #pragma unroll
      for (int j = 0; j < 4; j++)
        acc[i][j] = __builtin_amdgcn_mfma_f32_16x16x32_bf16(av[i], bv[j], acc[i][j], 0, 0, 0);
    if (t + 2 < NT){
      int s2 = cur + 2; if (s2 >= 3) s2 -= 3;
      STAGE(s2, kof(t + 2));
    }
    cur = (cur == 2) ? 0 : cur + 1;
  }

  if constexpr (OUTMODE == 2){
    const float SCQ = 0.125f * 1.44269504088896341f;
    #pragma unroll
    for (int i = 0; i < 4; i++){
      const int row0 = m0 + wr*64 + i*16 + l4*4;
      const size_t rQK = (size_t)(row0>>5)*2048 + (size_t)(row0&31)*8;
      // permuted V slot: ks=(row>>4)&1, hi'=(row>>2)&1, i0=4*((row>>3)&1)
      const size_t rV  = (size_t)(row0>>5)*2048 + (size_t)((row0>>4)&1)*1024
                       + (size_t)((row0>>2)&1)*256 + (size_t)((row0>>3)&1)*4;
      #pragma unroll
      for (int j = 0; j < 4; j++){
        const int col = n0 + wc*64 + j*16 + l15;
        const float bval = bias[col];
        if (col < 1536){
          const int isQ = (col < 768);
          const float qs = isQ ? SCQ : 1.f;
          const int c2 = isQ ? col : (col - 768);
          short* dst = isQ ? outB : outB2;
          const int head = c2 >> 6, dh = c2 & 63;
          const size_t base = (size_t)head*262144 + (size_t)(dh>>4)*512
                            + (size_t)((dh>>3)&1)*256 + (size_t)(dh&7) + rQK;
          dst[base]      = (short)f2b((acc[i][j][0] + bval) * qs);
          dst[base + 8]  = (short)f2b((acc[i][j][1] + bval) * qs);
          dst[base + 16] = (short)f2b((acc[i][j][2] + bval) * qs);
          dst[base + 24] = (short)f2b((acc[i][j][3] + bval) * qs);
        } else {
          const int c2 = col - 1536;
          const int head = c2 >> 6, dh = c2 & 63;
          const size_t base = (size_t)head*262144 + (size_t)(dh>>5)*512
                            + (size_t)(dh&31)*8 + rV;
          short4v sv;
          sv[0] = (short)f2b(acc[i][j][0] + bval);
          sv[1] = (short)f2b(acc[i][j][1] + bval);
          sv[2] = (short)f2b(acc[i][j][2] + bval);
          sv[3] = (short)f2b(acc[i][j][3] + bval);
          *(short4v*)(outB3 + base) = sv;
        }
      }
    }
  } else if constexpr (OUTMODE == 3){
    float* dst = sb ? outF2 : outF;
    #pragma unroll
    for (int i = 0; i < 4; i++){
      const int row0 = m0 + wr*64 + i*16 + l4*4;
      #pragma unroll
      for (int j = 0; j < 4; j++){
        const int col = n0 + wc*64 + j*16 + l15;
        #pragma unroll
        for (int jj = 0; jj < 4; jj++)
          dst[(size_t)(row0 + jj)*N + col] = acc[i][j][jj];
      }
    }
  } else {
    #pragma unroll
    for (int i = 0; i < 4; i++){
      const int row0 = m0 + wr*64 + i*16 + l4*4;
      #pragma unroll
      for (int j = 0; j < 4; j++){
        const int col = n0 + wc*64 + j*16 + l15;
        const float bval = bias[col];
        #pragma unroll
        for (int jj = 0; jj < 4; jj++){
          float v = acc[i][j][jj] + bval;
          if constexpr (GELU) v = gelu_tanh(v);
          outB[(size_t)(row0 + jj)*N + col] = (short)f2b(v);
        }
      }
    }
  }
}

// ---- flash attention v9 (best measured): zero-routing PV (V k-slots
// permuted to match P's D-layout ownership), zero-LDS main loop,
// XCD-chunked grid, Q pre-scaled in qkv epilogue.
__global__ __launch_bounds__(256) void attn9_kernel(
    const short* __restrict__ Qf, const short* __restrict__ Kf,
    const short* __restrict__ Vf, short* __restrict__ hout){
  __shared__ float Ols[4][32][33];
  __shared__ float Lls[4][32];
  const int g = (blockIdx.x & 7) * 192 + (blockIdx.x >> 3);
  const int head = g >> 7;
  const int qt = g & 127;
  const int lane = threadIdx.x & 63, w = threadIdx.x >> 6;
  const int l31 = lane & 31, hi = lane >> 5;

  bf16x8 qf0, qf1, qf2, qf3;
  {
    const short* qp = Qf + (size_t)(head*128 + qt)*2048 + lane*8;
    qf0 = *(const bf16x8*)(qp);
    qf1 = *(const bf16x8*)(qp + 512);
    qf2 = *(const bf16x8*)(qp + 1024);
    qf3 = *(const bf16x8*)(qp + 1536);
  }

  float l_run = 0.f;
  f32x16 o0, o1;
  #pragma unroll
  for (int r = 0; r < 16; r++){ o0[r] = 0.f; o1[r] = 0.f; }

  const short* kp0 = Kf + (size_t)(head*128 + w*32)*2048 + lane*8;
  const short* vp0 = Vf + (size_t)(head*128 + w*32)*2048 + lane*8;

  auto PROC = [&](bf16x8 k0, bf16x8 k1, bf16x8 k2, bf16x8 k3, int t){
    const short* vp = vp0 + t*2048;
    bf16x8 v00 = *(const bf16x8*)(vp);            // ks=0, db=0 (permuted slots)
    bf16x8 v01 = *(const bf16x8*)(vp + 512);      // ks=0, db=1
    bf16x8 v10 = *(const bf16x8*)(vp + 1024);     // ks=1, db=0
    bf16x8 v11 = *(const bf16x8*)(vp + 1536);     // ks=1, db=1

    f32x16 s;
    #pragma unroll
    for (int r = 0; r < 16; r++) s[r] = 0.f;
    s = __builtin_amdgcn_mfma_f32_32x32x16_bf16(k0, qf0, s, 0, 0, 0);
    s = __builtin_amdgcn_mfma_f32_32x32x16_bf16(k1, qf1, s, 0, 0, 0);
    s = __builtin_amdgcn_mfma_f32_32x32x16_bf16(k2, qf2, s, 0, 0, 0);
    s = __builtin_amdgcn_mfma_f32_32x32x16_bf16(k3, qf3, s, 0, 0, 0);

    #pragma unroll
    for (int r = 0; r < 16; r++) s[r] = __builtin_amdgcn_exp2f(s[r]);
    float c0s = (s[0]+s[1]) + (s[2]+s[3]);
    float c1s = (s[4]+s[5]) + (s[6]+s[7]);
    float c2s = (s[8]+s[9]) + (s[10]+s[11]);
    float c3s = (s[12]+s[13]) + (s[14]+s[15]);
    l_run += pair_sum((c0s + c1s) + (c2s + c3s));

    // P^T B-fragments: lane-local pack only (V slot permutation absorbs routing)
    uint4v u0 = { pk_tr(s[0], s[1]),  pk_tr(s[2], s[3]),
                  pk_tr(s[4], s[5]),  pk_tr(s[6], s[7]) };
    uint4v u1 = { pk_tr(s[8], s[9]),  pk_tr(s[10], s[11]),
                  pk_tr(s[12], s[13]), pk_tr(s[14], s[15]) };
    bf16x8 pb0 = __builtin_bit_cast(bf16x8, u0);
    bf16x8 pb1 = __builtin_bit_cast(bf16x8, u1);

    o0 = __builtin_amdgcn_mfma_f32_32x32x16_bf16(v00, pb0, o0, 0, 0, 0);
    o0 = __builtin_amdgcn_mfma_f32_32x32x16_bf16(v10, pb1, o0, 0, 0, 0);
    o1 = __builtin_amdgcn_mfma_f32_32x32x16_bf16(v01, pb0, o1, 0, 0, 0);
    o1 = __builtin_amdgcn_mfma_f32_32x32x16_bf16(v11, pb1, o1, 0, 0, 0);
  };

  bf16x8 kA0 = *(const bf16x8*)(kp0);
  bf16x8 kA1 = *(const bf16x8*)(kp0 + 512);
  bf16x8 kA2 = *(const bf16x8*)(kp0 + 1024);
  bf16x8 kA3 = *(const bf16x8*)(kp0 + 1536);
  for (int t = 0; t < 32; t += 2){
    const short* kpB = kp0 + (t+1)*2048;
    bf16x8 kB0 = *(const bf16x8*)(kpB);
    bf16x8 kB1 = *(const bf16x8*)(kpB + 512);
    bf16x8 kB2 = *(const bf16x8*)(kpB + 1024);
    bf16x8 kB3 = *(const bf16x8*)(kpB + 1536);
    PROC(kA0, kA1, kA2, kA3, t);
    const short* kpA = kp0 + ((t+2 < 32) ? (t+2) : 31)*2048;
    kA0 = *(const bf16x8*)(kpA);
    kA1 = *(const bf16x8*)(kpA + 512);
    kA2 = *(const bf16x8*)(kpA + 1024);
    kA3 = *(const bf16x8*)(kpA + 1536);
    PROC(kB0, kB1, kB2, kB3, t+1);
  }

  if (hi == 0) Lls[w][l31] = l_run;
  #pragma unroll
  for (int r = 0; r < 16; r++){
    int d = (r & 3) + 8*(r >> 2) + 4*hi;
    Ols[w][l31][d] = o0[r];
  }
  __syncthreads();
  const int t = threadIdx.x;
  const int q = t >> 2, dc = (t & 3) * 8;
  float inv;
  if (t < 128){
    float l = Lls[0][q] + Lls[1][q] + Lls[2][q] + Lls[3][q];
    inv = 1.f / l;
    bf16x8 res;
    #pragma unroll
    for (int j = 0; j < 8; j++){
      float o = Ols[0][q][dc+j] + Ols[1][q][dc+j]
              + Ols[2][q][dc+j] + Ols[3][q][dc+j];
      res[j] = (short)f2b(o * inv);
    }
    *(bf16x8*)(hout + (size_t)(qt*32 + q)*768 + head*64 + dc) = res;
  }
  __syncthreads();
  #pragma unroll
  for (int r = 0; r < 16; r++){
    int d = (r & 3) + 8*(r >> 2) + 4*hi;
    Ols[w][l31][d] = o1[r];
  }
  __syncthreads();
  if (t < 128){
    bf16x8 res;
    #pragma unroll
    for (int j = 0; j < 8; j++){
      float o = Ols[0][q][dc+j] + Ols[1][q][dc+j]
              + Ols[2][q][dc+j] + Ols[3][q][dc+j];
      res[j] = (short)f2b(o * inv);
    }
    *(bf16x8*)(hout + (size_t)(qt*32 + q)*768 + head*64 + 32 + dc) = res;
  }
}

// ---- LayerNorm with split-K merge: v = p0 + p1 + resid + cbias ----
template<int WRITE_BF16>
__global__ __launch_bounds__(256) void ln_merge_kernel(
    const float* __restrict__ p0, const float* __restrict__ p1,
    const float* __restrict__ resid, const float* __restrict__ cbias,
    const float* __restrict__ g, const float* __restrict__ b,
    float* __restrict__ outF, short* __restrict__ outB){
  const int row = blockIdx.x;
  const size_t base = (size_t)row * 768;
  const int t = threadIdx.x;
  float v[3];
  #pragma unroll
  for (int i = 0; i < 3; i++){
    int c = t + i*256;
    v[i] = p0[base + c] + p1[base + c] + resid[base + c] + cbias[c];
  }
  float s  = v[0] + v[1] + v[2];
  float s2 = v[0]*v[0] + v[1]*v[1] + v[2]*v[2];
  #pragma unroll
  for (int off = 1; off < 64; off <<= 1){
    s  += __shfl_xor(s,  off);
    s2 += __shfl_xor(s2, off);
  }
  __shared__ float red[8];
  if ((t & 63) == 0){ red[t >> 6] = s; red[4 + (t >> 6)] = s2; }
  __syncthreads();
  s  = red[0] + red[1] + red[2] + red[3];
  s2 = red[4] + red[5] + red[6] + red[7];
  const float mean = s * (1.f/768.f);
  const float rstd = rsqrtf(s2*(1.f/768.f) - mean*mean + 1e-5f);
  #pragma unroll
  for (int i = 0; i < 3; i++){
    int c = t + i*256;
    float y = g[c] * ((v[i] - mean) * rstd) + b[c];
    outF[base + c] = y;
    if constexpr (WRITE_BF16) outB[base + c] = (short)f2b(y);
  }
}

extern "C" void kernel_launch(void* const* d_in, const int* in_sizes, int n_in,
                              void* d_out, int out_size, void* d_ws, size_t ws_size,
                              hipStream_t stream){
  const float* x    = (const float*)d_in[0];
  const float* Wqkv = (const float*)d_in[1];
  const float* bqkv = (const float*)d_in[2];
  const float* Wo   = (const float*)d_in[3];
  const float* bo   = (const float*)d_in[4];
  const float* ln1w = (const float*)d_in[5];
  const float* ln1b = (const float*)d_in[6];
  const float* W1   = (const float*)d_in[7];
  const float* b1   = (const float*)d_in[8];
  const float* W2   = (const float*)d_in[9];
  const float* b2   = (const float*)d_in[10];
  const float* ln2w = (const float*)d_in[11];
  const float* ln2b = (const float*)d_in[12];
  float* out = (float*)d_out;

  char* ws = (char*)d_ws;
  short* WqkvT = (short*)(ws + 0);          //  2304x768 bf16
  short* WoT   = (short*)(ws + 3538944);    //   768x768
  short* W1T   = (short*)(ws + 4718592);    //  3072x768
  short* W2T   = (short*)(ws + 9437184);    //   768x3072
  short* xb    = (short*)(ws + 14155776);   //  4096x768
  short* Qfb   = (short*)(ws + 20447232);   //  12x128x2048 packed Q fragments
  short* Kfb   = (short*)(ws + 26738688);   //  12x128x2048 packed K fragments
  short* Vfb   = (short*)(ws + 33030144);   //  12x128x2048 packed V fragments
  short* hb    = (short*)(ws + 39321600);   //  4096x768
  float* res1  = (float*)(ws + 45613056);   //  fp32 plane (FFN2 partial 0)
  float* x1f   = (float*)(ws + 58195968);   //  4096x768 fp32
  short* x1b   = (short*)(ws + 70778880);   //  4096x768
  short* h1b   = (short*)(ws + 77070336);   //  4096x3072 (also Wo partials 0/1)
  float* woP   = (float*)(ws + 77070336);   //  2 fp32 planes (pre-FFN1)
  float* f2P1  = (float*)(ws + 20447232);   //  fp32 plane (Qf/Kf region, post-attn)
  const int PLANE = 4096*768;

  dim3 blk(256);
  // fused transposes + x convert (9984 blocks)
  prep_kernel<<<dim3(9984), blk, 0, stream>>>(
      Wqkv, WqkvT, Wo, WoT, W1, W1T, W2, W2T, x, xb);

  // qkv = x @ Wqkv + bqkv -> fragment-packed Q/K/V (Q pre-scaled); 576 blocks, chunk 9x8
  gemm_kernel<2,0><<<dim3(576), blk, 0, stream>>>(
      xb, WqkvT, bqkv, nullptr, nullptr, Qfb, Kfb, Vfb,
      4096, 2304, 768, 768, 576, 9, 2, 8);
  // flash attention -> h bf16 (1536 blocks, XCD-chunked)
  attn9_kernel<<<dim3(1536), blk, 0, stream>>>(Qfb, Kfb, Vfb, hb);
  // h @ Wo split-K=2 -> fp32 partials in h1b region (384 blocks, chunk 6x4)
  gemm_kernel<3,0><<<dim3(384), blk, 0, stream>>>(
      hb, WoT, nullptr, woP, woP + PLANE, nullptr, nullptr, nullptr,
      4096, 768, 768, 384, 192, 6, 1, 4);
  // x1 = LN1(p0 + p1 + x + bo)
  ln_merge_kernel<1><<<dim3(4096), blk, 0, stream>>>(
      woP, woP + PLANE, x, bo, ln1w, ln1b, x1f, x1b);
  // h1 = gelu(x1 @ W1 + b1) bf16; 768 blocks, chunk 12x8
  gemm_kernel<1,1><<<dim3(768), blk, 0, stream>>>(
      x1b, W1T, b1, nullptr, nullptr, h1b, nullptr, nullptr,
      4096, 3072, 768, 768, 768, 12, 2, 8);
  // h1 @ W2 split-K=2 -> fp32 partials res1 / f2P1 (384 blocks, chunk 6x4)
  gemm_kernel<3,0><<<dim3(384), blk, 0, stream>>>(
      h1b, W2T, nullptr, res1, f2P1, nullptr, nullptr, nullptr,
      4096, 768, 3072, 1536, 192, 6, 1, 4);
  // out = LN2(q0 + q1 + x1 + b2)
  ln_merge_kernel<0><<<dim3(4096), blk, 0, stream>>>(
      res1, f2P1, x1f, b2, ln2w, ln2b, out, nullptr);
}